// Round 11
// baseline (156.615 us; speedup 1.0000x reference)
//
#include <hip/hip_runtime.h>

#define NN 50000
#define NC 256
#define DD 64
#define HH 128
#define EVV 800000
#define EVC 400000
#define NE 1200000
#define NB 196              // coarse buckets of 256 vertices (d>>8)
#define BCAP 8192           // records per bucket region; mean 6122, +26 sigma
#define MLPV_B 1563         // ceil(NN/32)
#define MLPC_B 8            // NC/32
#define MLP_B (MLPV_B + MLPC_B)   // 1571
#define FILL_EPB 2048
#define FILL_B 586          // ceil(NE/2048)
#define K1_B (FILL_B * 4)   // period-4 interleave: 1 fill + 3 mlp per quad
#define GAT_B (NB * 8)      // 1568 blocks: 8 sub-blocks x 32 vertices / bucket
#define VCAP 64             // slots per vertex; Poisson(24), P(>64) ~ 1e-11
#define SPLIT 25000         // low/high table halves (3.2 MB each -> per-XCD L2)

__device__ __forceinline__ unsigned short f2bf(float x) {
  unsigned u = __float_as_uint(x);
  u = (u + 0x7fffu + ((u >> 16) & 1u)) >> 16;  // round-to-nearest-even
  return (unsigned short)u;
}

// LDS overlay: mlp (24 KB, fp32 tiles) and fill (~12.6 KB) never coexist.
union SMem {
  struct {
    float xs[4][64][8];    // 8 KB
    float hs[4][128][8];   // 16 KB
  } m;
  struct {
    int cnt[NB];
    int off[NB];
    int gbase[NB];
    int sa[256], sb[256];
    unsigned int stage[FILL_EPB];  // 8 KB
  } f;
};

// ---------------------------------------------------------------------------
// MLP for 32 rows (4 waves x 8 rows): table[r] = bf16(relu(X@W1+b1)@W2+b2).
// Transposed fp32 LDS tiles -> inner-loop b128 broadcasts; 16 FMAs / 2 W loads.
// ---------------------------------------------------------------------------
__device__ __forceinline__ void mlp32(
    const float* __restrict__ X, const float* __restrict__ W1,
    const float* __restrict__ b1, const float* __restrict__ W2,
    const float* __restrict__ b2, unsigned short* __restrict__ Y, int blk,
    int nrows, float (*xs)[64][8], float (*hs)[128][8]) {
  const int wave = threadIdx.x >> 6;
  const int lane = threadIdx.x & 63;
  const int row0 = (blk * 4 + wave) * 8;

  {
    float4 a, b;
    a.x = (row0 + 0 < nrows) ? X[(row0 + 0) * DD + lane] : 0.f;
    a.y = (row0 + 1 < nrows) ? X[(row0 + 1) * DD + lane] : 0.f;
    a.z = (row0 + 2 < nrows) ? X[(row0 + 2) * DD + lane] : 0.f;
    a.w = (row0 + 3 < nrows) ? X[(row0 + 3) * DD + lane] : 0.f;
    b.x = (row0 + 4 < nrows) ? X[(row0 + 4) * DD + lane] : 0.f;
    b.y = (row0 + 5 < nrows) ? X[(row0 + 5) * DD + lane] : 0.f;
    b.z = (row0 + 6 < nrows) ? X[(row0 + 6) * DD + lane] : 0.f;
    b.w = (row0 + 7 < nrows) ? X[(row0 + 7) * DD + lane] : 0.f;
    *(float4*)&xs[wave][lane][0] = a;
    *(float4*)&xs[wave][lane][4] = b;
  }
  __syncthreads();

  const float bias0 = b1[lane];
  const float bias1 = b1[lane + 64];
  float h0[8], h1[8];
#pragma unroll
  for (int r = 0; r < 8; ++r) { h0[r] = bias0; h1[r] = bias1; }

#pragma unroll 8
  for (int k = 0; k < 64; ++k) {
    const float4 xa = *(const float4*)&xs[wave][k][0];
    const float4 xb = *(const float4*)&xs[wave][k][4];
    const float wa = W1[k * HH + lane];
    const float wb = W1[k * HH + 64 + lane];
    h0[0] = fmaf(xa.x, wa, h0[0]); h1[0] = fmaf(xa.x, wb, h1[0]);
    h0[1] = fmaf(xa.y, wa, h0[1]); h1[1] = fmaf(xa.y, wb, h1[1]);
    h0[2] = fmaf(xa.z, wa, h0[2]); h1[2] = fmaf(xa.z, wb, h1[2]);
    h0[3] = fmaf(xa.w, wa, h0[3]); h1[3] = fmaf(xa.w, wb, h1[3]);
    h0[4] = fmaf(xb.x, wa, h0[4]); h1[4] = fmaf(xb.x, wb, h1[4]);
    h0[5] = fmaf(xb.y, wa, h0[5]); h1[5] = fmaf(xb.y, wb, h1[5]);
    h0[6] = fmaf(xb.z, wa, h0[6]); h1[6] = fmaf(xb.z, wb, h1[6]);
    h0[7] = fmaf(xb.w, wa, h0[7]); h1[7] = fmaf(xb.w, wb, h1[7]);
  }
  *(float4*)&hs[wave][lane][0] =
      make_float4(fmaxf(h0[0], 0.f), fmaxf(h0[1], 0.f), fmaxf(h0[2], 0.f),
                  fmaxf(h0[3], 0.f));
  *(float4*)&hs[wave][lane][4] =
      make_float4(fmaxf(h0[4], 0.f), fmaxf(h0[5], 0.f), fmaxf(h0[6], 0.f),
                  fmaxf(h0[7], 0.f));
  *(float4*)&hs[wave][lane + 64][0] =
      make_float4(fmaxf(h1[0], 0.f), fmaxf(h1[1], 0.f), fmaxf(h1[2], 0.f),
                  fmaxf(h1[3], 0.f));
  *(float4*)&hs[wave][lane + 64][4] =
      make_float4(fmaxf(h1[4], 0.f), fmaxf(h1[5], 0.f), fmaxf(h1[6], 0.f),
                  fmaxf(h1[7], 0.f));
  __syncthreads();

  const float bias2 = b2[lane];
  float a[8];
#pragma unroll
  for (int r = 0; r < 8; ++r) a[r] = bias2;

#pragma unroll 8
  for (int j = 0; j < HH; ++j) {
    const float4 ha = *(const float4*)&hs[wave][j][0];
    const float4 hb = *(const float4*)&hs[wave][j][4];
    const float w = W2[j * DD + lane];
    a[0] = fmaf(ha.x, w, a[0]);
    a[1] = fmaf(ha.y, w, a[1]);
    a[2] = fmaf(ha.z, w, a[2]);
    a[3] = fmaf(ha.w, w, a[3]);
    a[4] = fmaf(hb.x, w, a[4]);
    a[5] = fmaf(hb.y, w, a[5]);
    a[6] = fmaf(hb.z, w, a[6]);
    a[7] = fmaf(hb.w, w, a[7]);
  }
#pragma unroll
  for (int r = 0; r < 8; ++r)
    if (row0 + r < nrows) Y[(row0 + r) * DD + lane] = f2bf(a[r]);
}

// ---------------------------------------------------------------------------
// Fill branch: block-local counting sort into NB coarse buckets; ONE global
// atomic per (block,bucket) reserves a run at bucket*BCAP; bucket-ordered
// copy-out -> coalesced runs. Record = (d<<16)|s.
// ---------------------------------------------------------------------------
__device__ __forceinline__ void fill_block(
    const int* __restrict__ src_vv, const int* __restrict__ dst_vv,
    const int* __restrict__ src_vc, const int* __restrict__ dst_vc,
    int* __restrict__ gcur, unsigned int* __restrict__ records, int blk,
    SMem* sm) {
  const int t = threadIdx.x;
  const int base = blk * FILL_EPB;
  if (t < NB) sm->f.cnt[t] = 0;
  __syncthreads();

  unsigned int rec[8];
  int rk[8];
#pragma unroll
  for (int r = 0; r < 8; ++r) {
    const int e = base + r * 256 + t;
    rk[r] = -1;
    if (e < NE) {
      int s, d;
      if (e < EVV) {
        s = src_vv[e];
        d = dst_vv[e];
      } else {
        s = NN + src_vc[e - EVV];
        d = dst_vc[e - EVV];
      }
      rec[r] = ((unsigned int)d << 16) | (unsigned int)s;
      rk[r] = atomicAdd(&sm->f.cnt[d >> 8], 1);
    }
  }
  __syncthreads();

  const int val = (t < NB) ? sm->f.cnt[t] : 0;
  sm->f.sa[t] = val;
  __syncthreads();
  int* s = sm->f.sa;
  int* d = sm->f.sb;
  for (int o = 1; o < 256; o <<= 1) {
    d[t] = s[t] + ((t >= o) ? s[t - o] : 0);
    __syncthreads();
    int* tmp = s; s = d; d = tmp;
  }
  if (t < NB) {
    sm->f.off[t] = s[t] - val;
    sm->f.gbase[t] = t * BCAP + ((val > 0) ? atomicAdd(&gcur[t], val) : 0);
  }
  __syncthreads();

#pragma unroll
  for (int r = 0; r < 8; ++r)
    if (rk[r] >= 0) sm->f.stage[sm->f.off[rec[r] >> 24] + rk[r]] = rec[r];
  __syncthreads();

  const int total = (NE - base < FILL_EPB) ? (NE - base) : FILL_EPB;
  for (int i = t; i < total; i += 256) {
    const unsigned int u = sm->f.stage[i];
    const int b2 = u >> 24;  // = d >> 8
    records[sm->f.gbase[b2] + (i - sm->f.off[b2])] = u;
  }
}

// ---------------------------------------------------------------------------
// K1 fused, INTERLEAVED: quad q = {1 fill block, 3 mlp blocks}.
// ---------------------------------------------------------------------------
__global__ __launch_bounds__(256) void k1_kernel(
    const float* __restrict__ x_v, const float* __restrict__ x_c,
    const float* __restrict__ W1v, const float* __restrict__ b1v,
    const float* __restrict__ W2v, const float* __restrict__ b2v,
    const float* __restrict__ W1c, const float* __restrict__ b1c,
    const float* __restrict__ W2c, const float* __restrict__ b2c,
    const int* __restrict__ src_vv, const int* __restrict__ dst_vv,
    const int* __restrict__ src_vc, const int* __restrict__ dst_vc,
    unsigned short* __restrict__ table, int* __restrict__ gcur,
    unsigned int* __restrict__ records) {
  __shared__ SMem sm;
  const int q = blockIdx.x >> 2;
  const int r = blockIdx.x & 3;
  if (r == 0) {
    fill_block(src_vv, dst_vv, src_vc, dst_vc, gcur, records, q, &sm);
  } else {
    const int mb = q * 3 + (r - 1);
    if (mb >= MLP_B) return;
    if (mb < MLPV_B)
      mlp32(x_v, W1v, b1v, W2v, b2v, table, mb, NN, sm.m.xs, sm.m.hs);
    else
      mlp32(x_c, W1c, b1c, W2c, b2c, table + (size_t)NN * DD, mb - MLPV_B, NC,
            sm.m.xs, sm.m.hs);
  }
}

// ---------------------------------------------------------------------------
// Gather (TWO-PHASE TABLE SWEEP): block = 32 vertices. One placement pass
// builds two-ended per-vertex slot lists: low srcs (s<SPLIT) forward, high
// srcs + colors backward. All blocks then sweep the low table half (3.2 MB,
// per-XCD-L2-resident) before the high half -> converts L3-latency misses
// into L2 hits. x_v prefetched early (hidden under the record scan).
// ---------------------------------------------------------------------------
__device__ __forceinline__ void acc8(float* a, const uint4 t) {
  a[0] += __uint_as_float(t.x << 16);
  a[1] += __uint_as_float(t.x & 0xffff0000u);
  a[2] += __uint_as_float(t.y << 16);
  a[3] += __uint_as_float(t.y & 0xffff0000u);
  a[4] += __uint_as_float(t.z << 16);
  a[5] += __uint_as_float(t.z & 0xffff0000u);
  a[6] += __uint_as_float(t.w << 16);
  a[7] += __uint_as_float(t.w & 0xffff0000u);
}

__device__ __forceinline__ void place(unsigned int u, int sub, int* cLo,
                                      int* cHi, unsigned short* slots) {
  const int dd = u >> 16;
  if (((dd >> 5) & 7) == sub) {
    const int lv = dd & 31;
    const int s = u & 0xffffu;
    if (s < SPLIT) {
      const int pos = atomicAdd(&cLo[lv], 1);
      if (pos < VCAP) slots[lv * VCAP + pos] = (unsigned short)s;
    } else {
      const int pos = atomicAdd(&cHi[lv], 1);
      if (pos < VCAP) slots[lv * VCAP + (VCAP - 1 - pos)] = (unsigned short)s;
    }
  }
}

__device__ __forceinline__ void accrange(const uint4* __restrict__ table4,
                                         const unsigned short* __restrict__ sl,
                                         int i, int b, int c, float* a) {
  for (; i + 8 <= b; i += 8) {
    const int e0 = sl[i + 0];
    const int e1 = sl[i + 1];
    const int e2 = sl[i + 2];
    const int e3 = sl[i + 3];
    const int e4 = sl[i + 4];
    const int e5 = sl[i + 5];
    const int e6 = sl[i + 6];
    const int e7 = sl[i + 7];
    const uint4 t0 = table4[(size_t)e0 * 8 + c];
    const uint4 t1 = table4[(size_t)e1 * 8 + c];
    const uint4 t2 = table4[(size_t)e2 * 8 + c];
    const uint4 t3 = table4[(size_t)e3 * 8 + c];
    const uint4 t4 = table4[(size_t)e4 * 8 + c];
    const uint4 t5 = table4[(size_t)e5 * 8 + c];
    const uint4 t6 = table4[(size_t)e6 * 8 + c];
    const uint4 t7 = table4[(size_t)e7 * 8 + c];
    acc8(a, t0); acc8(a, t1); acc8(a, t2); acc8(a, t3);
    acc8(a, t4); acc8(a, t5); acc8(a, t6); acc8(a, t7);
  }
  for (; i + 4 <= b; i += 4) {
    const int e0 = sl[i + 0];
    const int e1 = sl[i + 1];
    const int e2 = sl[i + 2];
    const int e3 = sl[i + 3];
    const uint4 t0 = table4[(size_t)e0 * 8 + c];
    const uint4 t1 = table4[(size_t)e1 * 8 + c];
    const uint4 t2 = table4[(size_t)e2 * 8 + c];
    const uint4 t3 = table4[(size_t)e3 * 8 + c];
    acc8(a, t0); acc8(a, t1); acc8(a, t2); acc8(a, t3);
  }
  for (; i < b; ++i) {
    const uint4 t0 = table4[(size_t)sl[i] * 8 + c];
    acc8(a, t0);
  }
}

__global__ __launch_bounds__(256) void gather_kernel(
    const uint4* __restrict__ table4, const unsigned int* __restrict__ records,
    const int* __restrict__ gcur, const float4* __restrict__ xv4,
    float4* __restrict__ out4) {
  __shared__ int cLo[32];
  __shared__ int cHi[32];
  __shared__ unsigned short slots[32 * VCAP];  // 4 KB
  const int t = threadIdx.x;
  const int bucket = blockIdx.x >> 3;
  const int sub = blockIdx.x & 7;
  const int start = bucket * BCAP;
  const int nrec = gcur[bucket];

  // early x_v prefetch for this thread's vertex (independent of the scan)
  const int g = t >> 3;
  const int c = t & 7;
  const int v = bucket * 256 + sub * 32 + g;
  const size_t ob = (size_t)v * 16 + c * 2;
  float4 x0 = {0.f, 0.f, 0.f, 0.f}, x1 = x0;
  if (v < NN) {
    x0 = xv4[ob];
    x1 = xv4[ob + 1];
  }

  if (t < 32) { cLo[t] = 0; cHi[t] = 0; }
  __syncthreads();

  // single placement pass, uint4-vectorized (records base is 32KB-aligned)
  const uint4* rec4 = (const uint4*)(records + start);
  const int nfull = nrec >> 2;
  for (int q = t; q < nfull; q += 256) {
    const uint4 u = rec4[q];
    place(u.x, sub, cLo, cHi, slots);
    place(u.y, sub, cLo, cHi, slots);
    place(u.z, sub, cLo, cHi, slots);
    place(u.w, sub, cLo, cHi, slots);
  }
  for (int j = (nfull << 2) + t; j < nrec; j += 256)
    place(records[start + j], sub, cLo, cHi, slots);
  __syncthreads();

  if (v >= NN) return;
  int nLo = cLo[g];
  nLo = (nLo > VCAP) ? VCAP : nLo;
  int nHi = cHi[g];
  if (nHi > VCAP - nLo) nHi = VCAP - nLo;  // deg>64: clamp (P ~ 1e-11)
  const unsigned short* sl = slots + g * VCAP;

  float a[8];
#pragma unroll
  for (int r = 0; r < 8; ++r) a[r] = 0.f;

  accrange(table4, sl, 0, nLo, c, a);            // phase A: low half (L2)
  accrange(table4, sl, VCAP - nHi, VCAP, c, a);  // phase B: high half + colors

  float4 o0, o1;
  o0.x = fmaxf(x0.x + a[0], 0.f);
  o0.y = fmaxf(x0.y + a[1], 0.f);
  o0.z = fmaxf(x0.z + a[2], 0.f);
  o0.w = fmaxf(x0.w + a[3], 0.f);
  o1.x = fmaxf(x1.x + a[4], 0.f);
  o1.y = fmaxf(x1.y + a[5], 0.f);
  o1.z = fmaxf(x1.z + a[6], 0.f);
  o1.w = fmaxf(x1.w + a[7], 0.f);
  out4[ob] = o0;
  out4[ob + 1] = o1;
}

extern "C" void kernel_launch(void* const* d_in, const int* in_sizes, int n_in,
                              void* d_out, int out_size, void* d_ws,
                              size_t ws_size, hipStream_t stream) {
  const float* x_v = (const float*)d_in[0];
  const float* x_c = (const float*)d_in[1];
  const float* W1v = (const float*)d_in[2];
  const float* b1v = (const float*)d_in[3];
  const float* W2v = (const float*)d_in[4];
  const float* b2v = (const float*)d_in[5];
  const float* W1c = (const float*)d_in[6];
  const float* b1c = (const float*)d_in[7];
  const float* W2c = (const float*)d_in[8];
  const float* b2c = (const float*)d_in[9];
  const int* src_vv = (const int*)d_in[10];
  const int* dst_vv = (const int*)d_in[11];
  const int* src_vc = (const int*)d_in[12];
  const int* dst_vc = (const int*)d_in[13];
  float* out = (float*)d_out;

  // workspace: table(bf16) 6.43 MB | records 6.42 MB | gcur 784 B
  char* p = (char*)d_ws;
  unsigned short* table = (unsigned short*)p;
  p += (size_t)(NN + NC) * DD * sizeof(unsigned short);
  unsigned int* records = (unsigned int*)p;
  p += (size_t)NB * BCAP * sizeof(unsigned int);
  int* gcur = (int*)p;

  hipMemsetAsync(gcur, 0, NB * sizeof(int), stream);

  k1_kernel<<<K1_B, 256, 0, stream>>>(x_v, x_c, W1v, b1v, W2v, b2v, W1c, b1c,
                                      W2c, b2c, src_vv, dst_vv, src_vc, dst_vc,
                                      table, gcur, records);

  gather_kernel<<<GAT_B, 256, 0, stream>>>((const uint4*)table, records, gcur,
                                           (const float4*)x_v, (float4*)out);
}

// Round 12
// 149.741 us; speedup vs baseline: 1.0459x; 1.0459x over previous
//
#include <hip/hip_runtime.h>

#define NN 50000
#define NC 256
#define DD 64
#define HH 128
#define EVV 800000
#define EVC 400000
#define NE 1200000
#define NB 196              // coarse buckets of 256 vertices (d>>8)
#define BCAP 8192           // records per bucket region; mean 6122, +26 sigma
#define MLPV_B 3125         // ceil(NN/16)
#define MLPC_B 16           // NC/16
#define MLP_B (MLPV_B + MLPC_B)   // 3141 (16-row blocks)
#define FILL_EPB 2048
#define FILL_B 586          // ceil(NE/2048)
#define K1_B (FILL_B * 7)   // period-7 interleave: 1 fill + 6 mlp per septet
#define GAT_B (NB * 8)      // 1568 blocks: 8 sub-blocks x 32 vertices / bucket
#define VCAP 64             // slots per vertex; Poisson(24), P(>64) ~ 1e-11

__device__ __forceinline__ unsigned short f2bf(float x) {
  unsigned u = __float_as_uint(x);
  u = (u + 0x7fffu + ((u >> 16) & 1u)) >> 16;  // round-to-nearest-even
  return (unsigned short)u;
}

// LDS overlay: mlp (12 KB, 16-row fp32 tiles) and fill (~12.6 KB) never coexist.
union SMem {
  struct {
    float xs[4][64][4];    // 4 KB
    float hs[4][128][4];   // 8 KB
  } m;
  struct {
    int cnt[NB];
    int off[NB];
    int gbase[NB];
    int sa[256], sb[256];
    unsigned int stage[FILL_EPB];  // 8 KB
  } f;
};

// ---------------------------------------------------------------------------
// MLP for 16 rows (4 waves x 4 rows): table[r] = bf16(relu(X@W1+b1)@W2+b2).
// Half the per-block critical path of the 32-row version; 2x block count ->
// more block-level desync to hide W-load latency and barrier stalls.
// Inner loop reads stay wave-uniform b128 broadcasts.
// ---------------------------------------------------------------------------
__device__ __forceinline__ void mlp16(
    const float* __restrict__ X, const float* __restrict__ W1,
    const float* __restrict__ b1, const float* __restrict__ W2,
    const float* __restrict__ b2, unsigned short* __restrict__ Y, int blk,
    int nrows, float (*xs)[64][4], float (*hs)[128][4]) {
  const int wave = threadIdx.x >> 6;
  const int lane = threadIdx.x & 63;
  const int row0 = (blk * 4 + wave) * 4;

  {
    float4 a;
    a.x = (row0 + 0 < nrows) ? X[(row0 + 0) * DD + lane] : 0.f;
    a.y = (row0 + 1 < nrows) ? X[(row0 + 1) * DD + lane] : 0.f;
    a.z = (row0 + 2 < nrows) ? X[(row0 + 2) * DD + lane] : 0.f;
    a.w = (row0 + 3 < nrows) ? X[(row0 + 3) * DD + lane] : 0.f;
    *(float4*)&xs[wave][lane][0] = a;
  }
  __syncthreads();

  const float bias0 = b1[lane];
  const float bias1 = b1[lane + 64];
  float h0[4], h1[4];
#pragma unroll
  for (int r = 0; r < 4; ++r) { h0[r] = bias0; h1[r] = bias1; }

#pragma unroll 8
  for (int k = 0; k < 64; ++k) {
    const float4 xa = *(const float4*)&xs[wave][k][0];  // b128 broadcast
    const float wa = W1[k * HH + lane];                 // coalesced, L1-hot
    const float wb = W1[k * HH + 64 + lane];
    h0[0] = fmaf(xa.x, wa, h0[0]); h1[0] = fmaf(xa.x, wb, h1[0]);
    h0[1] = fmaf(xa.y, wa, h0[1]); h1[1] = fmaf(xa.y, wb, h1[1]);
    h0[2] = fmaf(xa.z, wa, h0[2]); h1[2] = fmaf(xa.z, wb, h1[2]);
    h0[3] = fmaf(xa.w, wa, h0[3]); h1[3] = fmaf(xa.w, wb, h1[3]);
  }
  *(float4*)&hs[wave][lane][0] =
      make_float4(fmaxf(h0[0], 0.f), fmaxf(h0[1], 0.f), fmaxf(h0[2], 0.f),
                  fmaxf(h0[3], 0.f));
  *(float4*)&hs[wave][lane + 64][0] =
      make_float4(fmaxf(h1[0], 0.f), fmaxf(h1[1], 0.f), fmaxf(h1[2], 0.f),
                  fmaxf(h1[3], 0.f));
  __syncthreads();

  const float bias2 = b2[lane];
  float a[4];
#pragma unroll
  for (int r = 0; r < 4; ++r) a[r] = bias2;

#pragma unroll 8
  for (int j = 0; j < HH; ++j) {
    const float4 ha = *(const float4*)&hs[wave][j][0];  // b128 broadcast
    const float w = W2[j * DD + lane];                  // coalesced, L1-hot
    a[0] = fmaf(ha.x, w, a[0]);
    a[1] = fmaf(ha.y, w, a[1]);
    a[2] = fmaf(ha.z, w, a[2]);
    a[3] = fmaf(ha.w, w, a[3]);
  }
#pragma unroll
  for (int r = 0; r < 4; ++r)
    if (row0 + r < nrows) Y[(row0 + r) * DD + lane] = f2bf(a[r]);
}

// ---------------------------------------------------------------------------
// Fill branch: block-local counting sort into NB coarse buckets; ONE global
// atomic per (block,bucket) reserves a run at bucket*BCAP; bucket-ordered
// copy-out -> coalesced runs. Record = (d<<16)|s.
// ---------------------------------------------------------------------------
__device__ __forceinline__ void fill_block(
    const int* __restrict__ src_vv, const int* __restrict__ dst_vv,
    const int* __restrict__ src_vc, const int* __restrict__ dst_vc,
    int* __restrict__ gcur, unsigned int* __restrict__ records, int blk,
    SMem* sm) {
  const int t = threadIdx.x;
  const int base = blk * FILL_EPB;
  if (t < NB) sm->f.cnt[t] = 0;
  __syncthreads();

  unsigned int rec[8];
  int rk[8];
#pragma unroll
  for (int r = 0; r < 8; ++r) {
    const int e = base + r * 256 + t;
    rk[r] = -1;
    if (e < NE) {
      int s, d;
      if (e < EVV) {
        s = src_vv[e];
        d = dst_vv[e];
      } else {
        s = NN + src_vc[e - EVV];
        d = dst_vc[e - EVV];
      }
      rec[r] = ((unsigned int)d << 16) | (unsigned int)s;
      rk[r] = atomicAdd(&sm->f.cnt[d >> 8], 1);
    }
  }
  __syncthreads();

  const int val = (t < NB) ? sm->f.cnt[t] : 0;
  sm->f.sa[t] = val;
  __syncthreads();
  int* s = sm->f.sa;
  int* d = sm->f.sb;
  for (int o = 1; o < 256; o <<= 1) {
    d[t] = s[t] + ((t >= o) ? s[t - o] : 0);
    __syncthreads();
    int* tmp = s; s = d; d = tmp;
  }
  if (t < NB) {
    sm->f.off[t] = s[t] - val;
    sm->f.gbase[t] = t * BCAP + ((val > 0) ? atomicAdd(&gcur[t], val) : 0);
  }
  __syncthreads();

#pragma unroll
  for (int r = 0; r < 8; ++r)
    if (rk[r] >= 0) sm->f.stage[sm->f.off[rec[r] >> 24] + rk[r]] = rec[r];
  __syncthreads();

  const int total = (NE - base < FILL_EPB) ? (NE - base) : FILL_EPB;
  for (int i = t; i < total; i += 256) {
    const unsigned int u = sm->f.stage[i];
    const int b2 = u >> 24;  // = d >> 8
    records[sm->f.gbase[b2] + (i - sm->f.off[b2])] = u;
  }
}

// ---------------------------------------------------------------------------
// K1 fused, INTERLEAVED period-7: septet q = {1 fill block, 6 mlp blocks}.
// 4102 blocks (~16/CU, ~2.7 residency generations at 12.6 KB LDS) -> block
// desync hides per-block barrier/latency stalls.
// ---------------------------------------------------------------------------
__global__ __launch_bounds__(256) void k1_kernel(
    const float* __restrict__ x_v, const float* __restrict__ x_c,
    const float* __restrict__ W1v, const float* __restrict__ b1v,
    const float* __restrict__ W2v, const float* __restrict__ b2v,
    const float* __restrict__ W1c, const float* __restrict__ b1c,
    const float* __restrict__ W2c, const float* __restrict__ b2c,
    const int* __restrict__ src_vv, const int* __restrict__ dst_vv,
    const int* __restrict__ src_vc, const int* __restrict__ dst_vc,
    unsigned short* __restrict__ table, int* __restrict__ gcur,
    unsigned int* __restrict__ records) {
  __shared__ SMem sm;
  const int q = blockIdx.x / 7;
  const int r = blockIdx.x % 7;
  if (r == 0) {
    fill_block(src_vv, dst_vv, src_vc, dst_vc, gcur, records, q, &sm);
  } else {
    const int mb = q * 6 + (r - 1);
    if (mb >= MLP_B) return;
    if (mb < MLPV_B)
      mlp16(x_v, W1v, b1v, W2v, b2v, table, mb, NN, sm.m.xs, sm.m.hs);
    else
      mlp16(x_c, W1c, b1c, W2c, b2c, table + (size_t)NN * DD, mb - MLPV_B, NC,
            sm.m.xs, sm.m.hs);
  }
}

// ---------------------------------------------------------------------------
// Gather (r10 form): block = 32 vertices (bucket blk>>3, eighth blk&7). ONE
// pass over the bucket's records (uint4-vectorized) places srcs into fixed
// 64-slot per-vertex LDS lists; then 8-lane groups accumulate bf16 table rows
// (8 in flight) + x_v + relu. x_v prefetched early.
// ---------------------------------------------------------------------------
__device__ __forceinline__ void acc8(float* a, const uint4 t) {
  a[0] += __uint_as_float(t.x << 16);
  a[1] += __uint_as_float(t.x & 0xffff0000u);
  a[2] += __uint_as_float(t.y << 16);
  a[3] += __uint_as_float(t.y & 0xffff0000u);
  a[4] += __uint_as_float(t.z << 16);
  a[5] += __uint_as_float(t.z & 0xffff0000u);
  a[6] += __uint_as_float(t.w << 16);
  a[7] += __uint_as_float(t.w & 0xffff0000u);
}

__device__ __forceinline__ void place(unsigned int u, int sub, int* c1,
                                      unsigned short* slots) {
  const int dd = u >> 16;
  if (((dd >> 5) & 7) == sub) {
    const int lv = dd & 31;
    const int pos = atomicAdd(&c1[lv], 1);
    if (pos < VCAP) slots[lv * VCAP + pos] = (unsigned short)(u & 0xffffu);
  }
}

__global__ __launch_bounds__(256) void gather_kernel(
    const uint4* __restrict__ table4, const unsigned int* __restrict__ records,
    const int* __restrict__ gcur, const float4* __restrict__ xv4,
    float4* __restrict__ out4) {
  __shared__ int c1[32];
  __shared__ unsigned short slots[32 * VCAP];  // 4 KB
  const int t = threadIdx.x;
  const int bucket = blockIdx.x >> 3;
  const int sub = blockIdx.x & 7;
  const int start = bucket * BCAP;
  const int nrec = gcur[bucket];

  // early x_v prefetch for this thread's vertex (independent of the scan)
  const int g = t >> 3;
  const int c = t & 7;
  const int v = bucket * 256 + sub * 32 + g;
  const size_t ob = (size_t)v * 16 + c * 2;
  float4 x0 = {0.f, 0.f, 0.f, 0.f}, x1 = x0;
  if (v < NN) {
    x0 = xv4[ob];
    x1 = xv4[ob + 1];
  }

  if (t < 32) c1[t] = 0;
  __syncthreads();

  // single placement pass, uint4-vectorized (records base is 32KB-aligned)
  const uint4* rec4 = (const uint4*)(records + start);
  const int nfull = nrec >> 2;
  for (int q = t; q < nfull; q += 256) {
    const uint4 u = rec4[q];
    place(u.x, sub, c1, slots);
    place(u.y, sub, c1, slots);
    place(u.z, sub, c1, slots);
    place(u.w, sub, c1, slots);
  }
  for (int j = (nfull << 2) + t; j < nrec; j += 256)
    place(records[start + j], sub, c1, slots);
  __syncthreads();

  if (v >= NN) return;
  int n = c1[g];
  n = (n > VCAP) ? VCAP : n;
  const unsigned short* sl = slots + g * VCAP;

  float a[8];
#pragma unroll
  for (int r = 0; r < 8; ++r) a[r] = 0.f;

  int i = 0;
  for (; i + 8 <= n; i += 8) {
    const int e0 = sl[i + 0];
    const int e1 = sl[i + 1];
    const int e2 = sl[i + 2];
    const int e3 = sl[i + 3];
    const int e4 = sl[i + 4];
    const int e5 = sl[i + 5];
    const int e6 = sl[i + 6];
    const int e7 = sl[i + 7];
    const uint4 t0 = table4[(size_t)e0 * 8 + c];
    const uint4 t1 = table4[(size_t)e1 * 8 + c];
    const uint4 t2 = table4[(size_t)e2 * 8 + c];
    const uint4 t3 = table4[(size_t)e3 * 8 + c];
    const uint4 t4 = table4[(size_t)e4 * 8 + c];
    const uint4 t5 = table4[(size_t)e5 * 8 + c];
    const uint4 t6 = table4[(size_t)e6 * 8 + c];
    const uint4 t7 = table4[(size_t)e7 * 8 + c];
    acc8(a, t0); acc8(a, t1); acc8(a, t2); acc8(a, t3);
    acc8(a, t4); acc8(a, t5); acc8(a, t6); acc8(a, t7);
  }
  for (; i + 4 <= n; i += 4) {
    const int e0 = sl[i + 0];
    const int e1 = sl[i + 1];
    const int e2 = sl[i + 2];
    const int e3 = sl[i + 3];
    const uint4 t0 = table4[(size_t)e0 * 8 + c];
    const uint4 t1 = table4[(size_t)e1 * 8 + c];
    const uint4 t2 = table4[(size_t)e2 * 8 + c];
    const uint4 t3 = table4[(size_t)e3 * 8 + c];
    acc8(a, t0); acc8(a, t1); acc8(a, t2); acc8(a, t3);
  }
  for (; i < n; ++i) {
    const uint4 t0 = table4[(size_t)sl[i] * 8 + c];
    acc8(a, t0);
  }

  float4 o0, o1;
  o0.x = fmaxf(x0.x + a[0], 0.f);
  o0.y = fmaxf(x0.y + a[1], 0.f);
  o0.z = fmaxf(x0.z + a[2], 0.f);
  o0.w = fmaxf(x0.w + a[3], 0.f);
  o1.x = fmaxf(x1.x + a[4], 0.f);
  o1.y = fmaxf(x1.y + a[5], 0.f);
  o1.z = fmaxf(x1.z + a[6], 0.f);
  o1.w = fmaxf(x1.w + a[7], 0.f);
  out4[ob] = o0;
  out4[ob + 1] = o1;
}

extern "C" void kernel_launch(void* const* d_in, const int* in_sizes, int n_in,
                              void* d_out, int out_size, void* d_ws,
                              size_t ws_size, hipStream_t stream) {
  const float* x_v = (const float*)d_in[0];
  const float* x_c = (const float*)d_in[1];
  const float* W1v = (const float*)d_in[2];
  const float* b1v = (const float*)d_in[3];
  const float* W2v = (const float*)d_in[4];
  const float* b2v = (const float*)d_in[5];
  const float* W1c = (const float*)d_in[6];
  const float* b1c = (const float*)d_in[7];
  const float* W2c = (const float*)d_in[8];
  const float* b2c = (const float*)d_in[9];
  const int* src_vv = (const int*)d_in[10];
  const int* dst_vv = (const int*)d_in[11];
  const int* src_vc = (const int*)d_in[12];
  const int* dst_vc = (const int*)d_in[13];
  float* out = (float*)d_out;

  // workspace: table(bf16) 6.43 MB | records 6.42 MB | gcur 784 B
  char* p = (char*)d_ws;
  unsigned short* table = (unsigned short*)p;
  p += (size_t)(NN + NC) * DD * sizeof(unsigned short);
  unsigned int* records = (unsigned int*)p;
  p += (size_t)NB * BCAP * sizeof(unsigned int);
  int* gcur = (int*)p;

  hipMemsetAsync(gcur, 0, NB * sizeof(int), stream);

  k1_kernel<<<K1_B, 256, 0, stream>>>(x_v, x_c, W1v, b1v, W2v, b2v, W1c, b1c,
                                      W2c, b2c, src_vv, dst_vv, src_vc, dst_vc,
                                      table, gcur, records);

  gather_kernel<<<GAT_B, 256, 0, stream>>>((const uint4*)table, records, gcur,
                                           (const float4*)x_v, (float4*)out);
}